// Round 16
// baseline (173.988 us; speedup 1.0000x reference)
//
#include <hip/hip_runtime.h>
#include <hip/hip_bf16.h>
#include <hip/hip_fp16.h>

// Menon 2007 demosaic (RGGB) + wb + clip + global minmax-normalize + gamma.
// Pass 1: fused tiled demosaic. GH/GV recomputed on the fly; D_H/D_V
//         parity-packed; stages A/B parity-specialized (literal p/q).
//         CFA plane is XOR-SWIZZLED at quad granularity:
//           cfa_q(r,q) = r*64 + (((q&7)^(r&7))|(q&8))*4
//         so lanes reading the same column window across rows hit distinct
//         bank-quads (kills the 7-way conflicts of the row-step-2 loops).
//         Every CFA access is a single aligned quad -> pure addressing change.
//         LDS 26752 B -> 6 blocks/CU. Output x*2^20 fp16 in d_ws.
// Pass 2: read fp16, normalize, gamma via v_log_f32/v_exp_f32.
//
// The M = (d_V >= d_H) classifier is a discrete decision on ~1e-5-scale values
// amplified ~4e4x by the normalize. The chain feeding M is BIT-EXACT vs numpy:
// contract off, true /65535.0f, reference accumulation order. Only addressing
// changed this revision - identical values.
#pragma clang fp contract(off)

constexpr int IMG_H = 3072;
constexpr int IMG_W = 4096;
constexpr int TS = 32;
constexpr float GAMMA_E = (float)(1.0 / 2.2);
constexpr float SC = 1048576.0f;        // 2^20
constexpr float INV_SC = 1.0f / SC;

__device__ __forceinline__ int mir(int v, int n) {
    v = (v < 0) ? -v : v;
    return (v >= n) ? (2 * n - 2 - v) : v;
}

// ---- LDS layout (floats). CFA XOR-swizzled; D staggered; G/HV odd-quad. ----
constexpr int CFA_ROWF = 64;   // 16 quads per row, XOR-swizzled
constexpr int D_ROWSP  = 24;   // + 4-float shift on alternate row pairs
constexpr int G_STR    = 36;   // 9 quads (row-step-1 access: Latin-square safe)
constexpr int HV_STR   = 36;
constexpr int OFF_CFA = 0;                   // 46 rows x 64 = 2944
constexpr int OFF_G   = 2944;                // 36 x 36 = 1296; M in low bit
constexpr int OFF_DH  = OFF_G + 36*36;       // 4240: 40 rows staggered = 964
constexpr int OFF_DV  = OFF_DH + 964;        // 5204: 964 -> 6168
constexpr int OFF_HH  = OFF_DH;              // 34 x 36 = 1224 (alias dead D)
constexpr int OFF_VV  = OFF_HH + 34*36;      // 5464: 1224 -> 6688
constexpr int SMEM_N  = OFF_VV + 34*36;      // 6688 floats = 26752 B

// CFA quad address: row r, quad q (0..15 used 0..10); XOR low-3 quad bits.
__device__ __forceinline__ int cfa_q(int r, int q) {
    return OFF_CFA + r * CFA_ROWF + ((((q) & 7) ^ (r & 7)) | ((q) & 8)) * 4;
}
__device__ __forceinline__ int d_row(int rr) {
    return rr * D_ROWSP + (((rr) >> 1) & 1) * 4;
}

__global__ void init_slots(unsigned int* slots) {
    int t = threadIdx.x;
    if (t < 512) slots[t] = (t < 256) ? 0x7F800000u : 0u;
}

__device__ __forceinline__ float pack_gm(float g, unsigned mb) {
    return __uint_as_float((__float_as_uint(g) & ~1u) | mb);
}

template <bool FP16>
__global__ __launch_bounds__(256, 6) void demosaic_pass1(
    const float* __restrict__ raw, const float* __restrict__ wb,
    float* __restrict__ out, __half* __restrict__ hout,
    unsigned int* __restrict__ slots)
{
    __shared__ __align__(16) float sm[SMEM_N];
    __shared__ float redmn[4], redmx[4];
    const int tid = threadIdx.x;
    const int gr0 = blockIdx.y * TS;   // even
    const int gc0 = blockIdx.x * TS;   // even
    const bool fast = (blockIdx.x != 0) && (blockIdx.x != gridDim.x - 1) &&
                      (blockIdx.y != 0) && (blockIdx.y != gridDim.y - 1);

    if (fast) {
        // ---- Stage 0: global float4 -> LDS b128 (swizzled quad), /65535.0f ----
        const float* src = raw + (long long)(gr0 - 6) * IMG_W + (gc0 - 4);
        auto doLoad = [&](int ar, int qd) {
            float4 v = *(const float4*)(src + ar * IMG_W + (qd << 2));
            *(float4*)&sm[cfa_q(ar, qd)] =
                make_float4(v.x / 65535.0f, v.y / 65535.0f, v.z / 65535.0f, v.w / 65535.0f);
        };
        for (int i = tid; i < 368; i += 256) doLoad(i >> 3, i & 7);
        for (int i = tid; i < 138; i += 256) doLoad(i / 3, 8 + (i % 3));
        __syncthreads();

        // ---- Stage A: packed D_H/D_V, parity-specialized (p literal) ----
        // Row ar <-> global r = gr0+ar-4 (CFA row ar+2). dl = 2k + p.
        auto doA = [&](int ar, int ku, int p) {
            const int q0 = 2 * ku;
            float w[16];
            {
                const float4 a = *(const float4*)&sm[cfa_q(ar + 2, q0)];
                const float4 b = *(const float4*)&sm[cfa_q(ar + 2, q0 + 1)];
                const float4 c = *(const float4*)&sm[cfa_q(ar + 2, q0 + 2)];
                const float4 d = *(const float4*)&sm[cfa_q(ar + 2, q0 + 3)];
                w[0]=a.x; w[1]=a.y; w[2]=a.z; w[3]=a.w;
                w[4]=b.x; w[5]=b.y; w[6]=b.z; w[7]=b.w;
                w[8]=c.x; w[9]=c.y; w[10]=c.z; w[11]=c.w;
                w[12]=d.x; w[13]=d.y; w[14]=d.z; w[15]=d.w;
            }
            float cvj[7][4];  // rows ar..ar+6, cols cc = 8ku+2+2j+p
#pragma unroll
            for (int k = 0; k < 7; ++k) {
                if (k == 2) {
                    cvj[2][0]=w[2+p]; cvj[2][1]=w[4+p]; cvj[2][2]=w[6+p]; cvj[2][3]=w[8+p];
                    continue;
                }
                int rr = ar + k;
                float2 e  = *(const float2*)&sm[cfa_q(rr, q0) + 2];
                float4 f  = *(const float4*)&sm[cfa_q(rr, q0 + 1)];
                float2 g2 = *(const float2*)&sm[cfa_q(rr, q0 + 2)];
                if (p == 0) { cvj[k][0]=e.x; cvj[k][1]=f.x; cvj[k][2]=f.z; cvj[k][3]=g2.x; }
                else        { cvj[k][0]=e.y; cvj[k][1]=f.y; cvj[k][2]=f.w; cvj[k][3]=g2.y; }
            }
            auto ghe = [&](int wi) -> float {
                float x0 = w[wi];
                float t0 = 0.5f * w[wi-1] + 0.5f * w[wi+1];
                float t1 = (-0.25f * w[wi-2] + 0.5f * x0) + (-0.25f * w[wi+2]);
                return t0 + t1;
            };
            auto gve = [&](int k0, int j2) -> float {
                float x0 = cvj[k0][j2];
                float t0 = 0.5f * cvj[k0-1][j2] + 0.5f * cvj[k0+1][j2];
                float t1 = (-0.25f * cvj[k0-2][j2] + 0.5f * x0) + (-0.25f * cvj[k0+2][j2]);
                return t0 + t1;
            };
            float ch[5];
#pragma unroll
            for (int m = 0; m < 5; ++m) {
                int wi = 2 * m + 2 + p;
                ch[m] = w[wi] - ghe(wi);
            }
            float dhp[4], dvp[4];
#pragma unroll
            for (int j = 0; j < 4; ++j) {
                dhp[j] = fabsf(ch[j] - ch[j + 1]);
                float gv0 = gve(2, j), gv2 = gve(4, j);
                float cv0 = cvj[2][j] - gv0, cv2 = cvj[4][j] - gv2;
                dvp[j] = fabsf(cv0 - cv2);
            }
            *(float4*)&sm[OFF_DH + d_row(ar) + 4*ku] = make_float4(dhp[0],dhp[1],dhp[2],dhp[3]);
            *(float4*)&sm[OFF_DV + d_row(ar) + 4*ku] = make_float4(dvp[0],dvp[1],dvp[2],dvp[3]);
        };
        for (int i = tid; i < 100; i += 256) doA(2 * (i / 5), i % 5, 0);
        for (int i = tid; i < 100; i += 256) doA(2 * (i / 5) + 1, i % 5, 1);
        __syncthreads();

        // ---- Stage B: d_H/d_V -> M, G, parity-specialized (q literal) ----
        auto doB = [&](int ar, int ku, int q) {
            const int k4 = 4 * ku;
            const int q0 = 2 * ku;
            float hw[6], vw[6], hu[4], hd[4], vu[4], vd[4];
            {
                int b0 = OFF_DH + d_row(ar + 2) + k4;
                float4 t = *(const float4*)&sm[b0]; hw[0]=t.x; hw[1]=t.y; hw[2]=t.z; hw[3]=t.w;
                float2 u = *(const float2*)&sm[b0 + 4]; hw[4]=u.x; hw[5]=u.y;
                float4 a = *(const float4*)&sm[OFF_DH + d_row(ar) + k4];     hu[0]=a.x; hu[1]=a.y; hu[2]=a.z; hu[3]=a.w;
                float4 b = *(const float4*)&sm[OFF_DH + d_row(ar + 4) + k4]; hd[0]=b.x; hd[1]=b.y; hd[2]=b.z; hd[3]=b.w;
                int v0 = OFF_DV + d_row(ar + 2) + k4;
                float4 t2 = *(const float4*)&sm[v0]; vw[0]=t2.x; vw[1]=t2.y; vw[2]=t2.z; vw[3]=t2.w;
                float2 u2 = *(const float2*)&sm[v0 + 4]; vw[4]=u2.x; vw[5]=u2.y;
                float4 a2 = *(const float4*)&sm[OFF_DV + d_row(ar) + k4];     vu[0]=a2.x; vu[1]=a2.y; vu[2]=a2.z; vu[3]=a2.w;
                float4 b2 = *(const float4*)&sm[OFF_DV + d_row(ar + 4) + k4]; vd[0]=b2.x; vd[1]=b2.y; vd[2]=b2.z; vd[3]=b2.w;
            }
            float w2[12];
            {
                const float4 a = *(const float4*)&sm[cfa_q(ar + 4, q0)];
                const float4 b = *(const float4*)&sm[cfa_q(ar + 4, q0 + 1)];
                const float4 c = *(const float4*)&sm[cfa_q(ar + 4, q0 + 2)];
                w2[0]=a.x; w2[1]=a.y; w2[2]=a.z; w2[3]=a.w;
                w2[4]=b.x; w2[5]=b.y; w2[6]=b.z; w2[7]=b.w;
                w2[8]=c.x; w2[9]=c.y; w2[10]=c.z; w2[11]=c.w;
            }
            float cwj[5][4];  // CFA rows ar+2..ar+6, cols cc = 8ku+2+2j+q
#pragma unroll
            for (int k = 0; k < 5; ++k) {
                if (k == 2) {
                    cwj[2][0]=w2[2+q]; cwj[2][1]=w2[4+q]; cwj[2][2]=w2[6+q]; cwj[2][3]=w2[8+q];
                    continue;
                }
                int rr = ar + 2 + k;
                float2 e  = *(const float2*)&sm[cfa_q(rr, q0) + 2];
                float4 f  = *(const float4*)&sm[cfa_q(rr, q0 + 1)];
                float2 g2 = *(const float2*)&sm[cfa_q(rr, q0 + 2)];
                if (q == 0) { cwj[k][0]=e.x; cwj[k][1]=f.x; cwj[k][2]=f.z; cwj[k][3]=g2.x; }
                else        { cwj[k][0]=e.y; cwj[k][1]=f.y; cwj[k][2]=f.w; cwj[k][3]=g2.y; }
            }
            auto ghe2 = [&](int wi) -> float {
                float x0 = w2[wi];
                float t0 = 0.5f * w2[wi-1] + 0.5f * w2[wi+1];
                float t1 = (-0.25f * w2[wi-2] + 0.5f * x0) + (-0.25f * w2[wi+2]);
                return t0 + t1;
            };
            auto gve2 = [&](int j2) -> float {
                float x0 = cwj[2][j2];
                float t0 = 0.5f * cwj[1][j2] + 0.5f * cwj[3][j2];
                float t1 = (-0.25f * cwj[0][j2] + 0.5f * x0) + (-0.25f * cwj[4][j2]);
                return t0 + t1;
            };
            float gnb[4];
#pragma unroll
            for (int j = 0; j < 4; ++j) {
                float Dh0 = hw[j];
                float trowH = 3.0f*Dh0 + 3.0f*hw[j+1];
                float tcolH = (hu[j] + 3.0f*Dh0) + hd[j];
                float dH = (trowH + tcolH) - 3.0f*Dh0;
                float Dv0 = vw[j];
                float trowV = 3.0f*Dv0 + 3.0f*vw[j+1];
                float tcolV = (vu[j] + 3.0f*Dv0) + vd[j];
                float dV = (trowV + tcolV) - 3.0f*Dv0;
                unsigned mb = (dV >= dH) ? 1u : 0u;
                float gsel = mb ? ghe2(2*j + 2 + q) : gve2(j);
                gnb[j] = pack_gm(gsel, mb);
            }
            int gb = OFF_G + ar * G_STR + 8 * ku;
            if (q == 0) {
                *(float4*)&sm[gb] = make_float4(gnb[0], w2[3], gnb[1], w2[5]);
                if (ku < 4) *(float4*)&sm[gb+4] = make_float4(gnb[2], w2[7], gnb[3], w2[9]);
            } else {
                *(float4*)&sm[gb] = make_float4(w2[2], gnb[0], w2[4], gnb[1]);
                if (ku < 4) *(float4*)&sm[gb+4] = make_float4(w2[6], gnb[2], w2[8], gnb[3]);
            }
        };
        for (int i = tid; i < 90; i += 256) doB(2 * (i / 5), i % 5, 0);
        for (int i = tid; i < 90; i += 256) doB(2 * (i / 5) + 1, i % 5, 1);
        __syncthreads();

        // ---- Stage C: Hh/Vv (34 rows x 9 quads; alias dead D region) ----
        auto doC = [&](int ar, int hc4) {
            const int hq = hc4 >> 2;
            const float4 gmA = *(const float4*)&sm[OFF_G + (ar+1)*G_STR + hc4];
            const float4 gmB = *(const float4*)&sm[OFF_G + (ar+1)*G_STR + hc4 + 4];
            float gm[8] = {gmA.x,gmA.y,gmA.z,gmA.w, gmB.x,gmB.y,gmB.z,gmB.w};
            const float4 guA = *(const float4*)&sm[OFF_G + ar*G_STR + hc4];
            const float4 guB = *(const float4*)&sm[OFF_G + ar*G_STR + hc4 + 4];
            float gu[8] = {guA.x,guA.y,guA.z,guA.w, guB.x,guB.y,guB.z,guB.w};
            const float4 gdA = *(const float4*)&sm[OFF_G + (ar+2)*G_STR + hc4];
            const float4 gdB = *(const float4*)&sm[OFF_G + (ar+2)*G_STR + hc4 + 4];
            float gd[8] = {gdA.x,gdA.y,gdA.z,gdA.w, gdB.x,gdB.y,gdB.z,gdB.w};
            const float4 w5A = *(const float4*)&sm[cfa_q(ar + 5, hq)];
            const float4 w5B = *(const float4*)&sm[cfa_q(ar + 5, hq + 1)];
            float w5[8] = {w5A.x,w5A.y,w5A.z,w5A.w, w5B.x,w5B.y,w5B.z,w5B.w};
            const float4 w4A = *(const float4*)&sm[cfa_q(ar + 4, hq)];
            const float4 w4B = *(const float4*)&sm[cfa_q(ar + 4, hq + 1)];
            float w4[8] = {w4A.x,w4A.y,w4A.z,w4A.w, w4B.x,w4B.y,w4B.z,w4B.w};
            const float4 w6A = *(const float4*)&sm[cfa_q(ar + 6, hq)];
            const float4 w6B = *(const float4*)&sm[cfa_q(ar + 6, hq + 1)];
            float w6[8] = {w6A.x,w6A.y,w6A.z,w6A.w, w6B.x,w6B.y,w6B.z,w6B.w};
            float oh[4], ov[4];
#pragma unroll
            for (int j = 0; j < 4; ++j) {
                float g0 = gm[j + 1];
                oh[j] = g0 + 0.5f * (w5[j + 2] + w5[j + 4] - gm[j] - gm[j + 2]);
                ov[j] = g0 + 0.5f * (w4[j + 3] + w6[j + 3] - gu[j + 1] - gd[j + 1]);
            }
            *(float4*)&sm[OFF_HH + ar * HV_STR + hc4] = make_float4(oh[0],oh[1],oh[2],oh[3]);
            *(float4*)&sm[OFF_VV + ar * HV_STR + hc4] = make_float4(ov[0],ov[1],ov[2],ov[3]);
        };
        for (int i = tid; i < 272; i += 256) doC(i >> 3, (i & 7) << 2);
        for (int i = tid; i < 34; i += 256) doC(i, 32);
    } else {
        // ---------- border path: scalar + mir (exact reflect semantics) ----------
        auto CFAb = [&](int r, int c) -> float {
            int rr = r - gr0 + 6, cc = c - gc0 + 4;
            return sm[cfa_q(rr, cc >> 2) + (cc & 3)];
        };
        auto Gb   = [&](int r, int c) -> float { return sm[OFF_G   + (r - gr0 + 2) * G_STR   + (c - gc0 + 2)]; };
        auto DHL  = [&](int r, int c) -> float {
            int dr = r - gr0 + 4;
            int kk = ((c - gc0 + 2) - (dr & 1)) >> 1;
            return sm[OFF_DH + d_row(dr) + kk];
        };
        auto DVL  = [&](int r, int c) -> float {
            int dr = r - gr0 + 4;
            int kk = ((c - gc0 + 2) - (dr & 1)) >> 1;
            return sm[OFF_DV + d_row(dr) + kk];
        };
        auto ghB = [&](int r, int c) -> float {
            float x0 = CFAb(r, c);
            float t0 = 0.5f * CFAb(r, c - 1) + 0.5f * CFAb(r, c + 1);
            float t1 = (-0.25f * CFAb(r, c - 2) + 0.5f * x0) + (-0.25f * CFAb(r, c + 2));
            return t0 + t1;
        };
        auto gvB = [&](int r, int c) -> float {
            float x0 = CFAb(r, c);
            float t0 = 0.5f * CFAb(r - 1, c) + 0.5f * CFAb(r + 1, c);
            float t1 = (-0.25f * CFAb(r - 2, c) + 0.5f * x0) + (-0.25f * CFAb(r + 2, c));
            return t0 + t1;
        };

        for (int i = tid; i < 46 * 44; i += 256) {
            int ar = i / 44, ac = i % 44;
            int r2 = mir(gr0 + ar - 6, IMG_H), c2 = mir(gc0 + ac - 4, IMG_W);
            sm[cfa_q(ar, ac >> 2) + (ac & 3)] = raw[r2 * IMG_W + c2] / 65535.0f;
        }
        __syncthreads();
        // Stage A border: packed D, k = 0..18 (k=19 unused)
        for (int i = tid; i < 40 * 19; i += 256) {
            int ar = i / 19, k = i % 19;
            int q = ar & 1, dl = 2 * k + q;
            int r2 = mir(gr0 + ar - 4, IMG_H), c2 = mir(gc0 + dl - 2, IMG_W);
            float ch0 = CFAb(r2, c2) - ghB(r2, c2);
            int c22 = mir(c2 + 2, IMG_W);
            float ch2 = CFAb(r2, c22) - ghB(r2, c22);
            sm[OFF_DH + d_row(ar) + k] = fabsf(ch0 - ch2);
            float cv0 = CFAb(r2, c2) - gvB(r2, c2);
            int r22 = mir(r2 + 2, IMG_H);
            float cv2 = CFAb(r22, c2) - gvB(r22, c2);
            sm[OFF_DV + d_row(ar) + k] = fabsf(cv0 - cv2);
        }
        __syncthreads();
        // Stage B border: full G plane (green copy; non-green M + selection)
        for (int i = tid; i < 36 * 36; i += 256) {
            int ar = i / 36, gc = i % 36;
            int r2 = mir(gr0 + ar - 2, IMG_H), c2 = mir(gc0 + gc - 2, IMG_W);
            float g;
            if ((r2 + c2) & 1) {
                g = CFAb(r2, c2);
            } else {
                float Dh0 = DHL(r2, c2);
                float trowH = 3.0f * Dh0 + 3.0f * DHL(r2, c2 + 2);
                float tcolH = (DHL(r2 - 2, c2) + 3.0f * Dh0) + DHL(r2 + 2, c2);
                float dH = (trowH + tcolH) - 3.0f * Dh0;
                float Dv0 = DVL(r2, c2);
                float trowV = 3.0f * Dv0 + 3.0f * DVL(r2, c2 + 2);
                float tcolV = (DVL(r2 - 2, c2) + 3.0f * Dv0) + DVL(r2 + 2, c2);
                float dV = (trowV + tcolV) - 3.0f * Dv0;
                unsigned mb = (dV >= dH) ? 1u : 0u;
                float gsel = mb ? ghB(r2, c2) : gvB(r2, c2);
                g = pack_gm(gsel, mb);
            }
            sm[OFF_G + ar * G_STR + gc] = g;
        }
        __syncthreads();
        // Stage C border
        for (int i = tid; i < 34 * 34; i += 256) {
            int ar = i / 34, ac = i % 34;
            int r2 = mir(gr0 + ar - 1, IMG_H), c2 = mir(gc0 + ac - 1, IMG_W);
            float g0 = Gb(r2, c2);
            float hh = g0 + 0.5f * (CFAb(r2, c2 - 1) + CFAb(r2, c2 + 1) - Gb(r2, c2 - 1) - Gb(r2, c2 + 1));
            float vv = g0 + 0.5f * (CFAb(r2 - 1, c2) + CFAb(r2 + 1, c2) - Gb(r2 - 1, c2) - Gb(r2 + 1, c2));
            sm[OFF_HH + ar * HV_STR + ac] = hh;
            sm[OFF_VV + ar * HV_STR + ac] = vv;
        }
        __syncthreads();   // extra barrier to match fast path count
    }
    __syncthreads();

    // ---------- final per-pixel: 1 row x 4 cols per thread ----------
    const float wr = wb[0], wg = wb[1], wbv = wb[2];
    const int pr = tid >> 3;
    const int pc0 = (tid & 7) << 2;
    const bool rowOdd = (pr & 1) != 0;      // gr0 even
    int hbase = OFF_HH + (pr + 1) * HV_STR + pc0;
    const float4 h1a = *(const float4*)&sm[hbase];
    const float4 h1b = *(const float4*)&sm[hbase + 4];
    float hwc[8] = {h1a.x, h1a.y, h1a.z, h1a.w, h1b.x, h1b.y, h1b.z, h1b.w};
    int vbase = OFF_VV + (pr + 1) * HV_STR + pc0;
    const float4 v1a = *(const float4*)&sm[vbase];
    const float4 v1b = *(const float4*)&sm[vbase + 4];
    float vwc[8] = {v1a.x, v1a.y, v1a.z, v1a.w, v1b.x, v1b.y, v1b.z, v1b.w};
    const float4 huA = *(const float4*)&sm[OFF_HH + pr * HV_STR + pc0];
    const float4 huB = *(const float4*)&sm[OFF_HH + pr * HV_STR + pc0 + 4];
    float hu[6] = {huA.x, huA.y, huA.z, huA.w, huB.x, huB.y};
    const float4 hdA = *(const float4*)&sm[OFF_HH + (pr + 2) * HV_STR + pc0];
    const float4 hdB = *(const float4*)&sm[OFF_HH + (pr + 2) * HV_STR + pc0 + 4];
    float hd[6] = {hdA.x, hdA.y, hdA.z, hdA.w, hdB.x, hdB.y};
    const float4 vuA = *(const float4*)&sm[OFF_VV + pr * HV_STR + pc0];
    const float4 vuB = *(const float4*)&sm[OFF_VV + pr * HV_STR + pc0 + 4];
    float vu[6] = {vuA.x, vuA.y, vuA.z, vuA.w, vuB.x, vuB.y};
    const float4 vdA = *(const float4*)&sm[OFF_VV + (pr + 2) * HV_STR + pc0];
    const float4 vdB = *(const float4*)&sm[OFF_VV + (pr + 2) * HV_STR + pc0 + 4];
    float vd[6] = {vdA.x, vdA.y, vdA.z, vdA.w, vdB.x, vdB.y};
    const float4 cfq = *(const float4*)&sm[cfa_q(pr + 6, (pc0 >> 2) + 1)];
    float cf[4] = {cfq.x, cfq.y, cfq.z, cfq.w};
    const float4 gA = *(const float4*)&sm[OFF_G + (pr + 2) * G_STR + pc0];
    const float4 gB = *(const float4*)&sm[OFF_G + (pr + 2) * G_STR + pc0 + 4];
    float ggr[4] = {gA.z, gA.w, gB.x, gB.y};

    float mn = 1e30f, mx = -1e30f;
    float rr[4], go[4], bo[4];
    __half hR[4], hG[4], hB[4];
#pragma unroll
    for (int j = 0; j < 4; ++j) {
        const float cfa = cf[j];
        const float g = ggr[j];
        const unsigned mb = __float_as_uint(g) & 1u;
        float sH = (hwc[j] - vwc[j]) + (hwc[j + 2] - vwc[j + 2]);
        float sV = (hu[j + 1] - vu[j + 1]) + (hd[j + 1] - vd[j + 1]);
        float X = mb ? (cfa - 0.5f * sH) : (cfa + 0.5f * sV);
        float R, B;
        if ((j & 1) == 0) {             // col even
            R = rowOdd ? vwc[j + 1] : cfa;
            B = rowOdd ? hwc[j + 1] : X;
        } else {                        // col odd
            R = rowOdd ? X : hwc[j + 1];
            B = rowOdd ? cfa : vwc[j + 1];
        }
        R = fminf(fmaxf(R * wr, 0.f), 1.f);
        float Gx = fminf(fmaxf(g * wg, 0.f), 1.f);
        B = fminf(fmaxf(B * wbv, 0.f), 1.f);
        if constexpr (FP16) {
            hR[j] = __float2half(R * SC);  R  = __half2float(hR[j]);
            hG[j] = __float2half(Gx * SC); Gx = __half2float(hG[j]);
            hB[j] = __float2half(B * SC);  B  = __half2float(hB[j]);
        }
        mn = fminf(mn, fminf(R, fminf(Gx, B)));
        mx = fmaxf(mx, fmaxf(R, fmaxf(Gx, B)));
        rr[j] = R; go[j] = Gx; bo[j] = B;
    }
    const long long HW = (long long)IMG_H * IMG_W;
    const long long base = (long long)(gr0 + pr) * IMG_W + (gc0 + pc0);
    if constexpr (FP16) {
        auto pack = [](__half a, __half b) {
            __half2 p = __halves2half2(a, b);
            return *reinterpret_cast<unsigned int*>(&p);
        };
        *(uint2*)(hout + base)          = make_uint2(pack(hR[0], hR[1]), pack(hR[2], hR[3]));
        *(uint2*)(hout + HW + base)     = make_uint2(pack(hG[0], hG[1]), pack(hG[2], hG[3]));
        *(uint2*)(hout + 2 * HW + base) = make_uint2(pack(hB[0], hB[1]), pack(hB[2], hB[3]));
    } else {
        *(float4*)(out + base)          = make_float4(rr[0], rr[1], rr[2], rr[3]);
        *(float4*)(out + HW + base)     = make_float4(go[0], go[1], go[2], go[3]);
        *(float4*)(out + 2 * HW + base) = make_float4(bo[0], bo[1], bo[2], bo[3]);
    }

#pragma unroll
    for (int off2 = 32; off2 > 0; off2 >>= 1) {
        mn = fminf(mn, __shfl_xor(mn, off2));
        mx = fmaxf(mx, __shfl_xor(mx, off2));
    }
    if ((tid & 63) == 0) { redmn[tid >> 6] = mn; redmx[tid >> 6] = mx; }
    __syncthreads();
    if (tid == 0) {
        mn = fminf(fminf(redmn[0], redmn[1]), fminf(redmn[2], redmn[3]));
        mx = fmaxf(fmaxf(redmx[0], redmx[1]), fmaxf(redmx[2], redmx[3]));
        if constexpr (FP16) { mn *= INV_SC; mx *= INV_SC; }
        int slot = (int)((blockIdx.y * gridDim.x + blockIdx.x) & 255);
        atomicMin(&slots[slot], __float_as_uint(mn));
        atomicMax(&slots[256 + slot], __float_as_uint(mx));
    }
}

__device__ __forceinline__ void reduce_slots(const unsigned int* slots, int tid,
                                             float* smn, float* smx, float& mn, float& mx) {
    mn = __uint_as_float(slots[tid]);
    mx = __uint_as_float(slots[256 + tid]);
#pragma unroll
    for (int off2 = 32; off2 > 0; off2 >>= 1) {
        mn = fminf(mn, __shfl_xor(mn, off2));
        mx = fmaxf(mx, __shfl_xor(mx, off2));
    }
    if ((tid & 63) == 0) { smn[tid >> 6] = mn; smx[tid >> 6] = mx; }
    __syncthreads();
    mn = fminf(fminf(smn[0], smn[1]), fminf(smn[2], smn[3]));
    mx = fmaxf(fmaxf(smx[0], smx[1]), fmaxf(smx[2], smx[3]));
}

__device__ __forceinline__ float gamma_hw(float a) {
    return __builtin_amdgcn_exp2f(GAMMA_E * __builtin_amdgcn_logf(a));
}

__global__ __launch_bounds__(256) void finalize_pass2_h(
    const __half* __restrict__ hin, float* __restrict__ out,
    const unsigned int* __restrict__ slots)
{
    __shared__ float smn[4], smx[4];
    const int tid = threadIdx.x;
    float mn, mx;
    reduce_slots(slots, tid, smn, smx, mn, mx);
    const float rng = mx - mn;
    const bool app = rng > 1e-6f;
    const float invden = 1.0f / fmaxf(rng, 1e-12f);

    const long long n8 = (long long)3 * IMG_H * IMG_W / 8;
    const uint4* pin = (const uint4*)hin;
    float4* po = (float4*)out;
    for (long long idx = (long long)blockIdx.x * blockDim.x + tid; idx < n8;
         idx += (long long)gridDim.x * blockDim.x) {
        uint4 u = pin[idx];
        float f[8];
        float2 t;
        t = __half22float2(*(__half2*)&u.x); f[0] = t.x; f[1] = t.y;
        t = __half22float2(*(__half2*)&u.y); f[2] = t.x; f[3] = t.y;
        t = __half22float2(*(__half2*)&u.z); f[4] = t.x; f[5] = t.y;
        t = __half22float2(*(__half2*)&u.w); f[6] = t.x; f[7] = t.y;
#pragma unroll
        for (int k = 0; k < 8; ++k) {
            float a = f[k] * INV_SC;
            a = app ? (a - mn) * invden : a;
            f[k] = gamma_hw(fmaxf(a, 1e-12f));
        }
        po[2 * idx]     = make_float4(f[0], f[1], f[2], f[3]);
        po[2 * idx + 1] = make_float4(f[4], f[5], f[6], f[7]);
    }
}

__global__ __launch_bounds__(256) void finalize_pass2_f(
    float* __restrict__ out, const unsigned int* __restrict__ slots)
{
    __shared__ float smn[4], smx[4];
    const int tid = threadIdx.x;
    float mn, mx;
    reduce_slots(slots, tid, smn, smx, mn, mx);
    const float rng = mx - mn;
    const bool app = rng > 1e-6f;
    const float invden = 1.0f / fmaxf(rng, 1e-12f);

    const long long n4 = (long long)3 * IMG_H * IMG_W / 4;
    float4* p = (float4*)out;
    for (long long idx = (long long)blockIdx.x * blockDim.x + tid; idx < n4;
         idx += (long long)gridDim.x * blockDim.x) {
        float4 v = p[idx];
        v.x = gamma_hw(fmaxf(app ? (v.x - mn) * invden : v.x, 1e-12f));
        v.y = gamma_hw(fmaxf(app ? (v.y - mn) * invden : v.y, 1e-12f));
        v.z = gamma_hw(fmaxf(app ? (v.z - mn) * invden : v.z, 1e-12f));
        v.w = gamma_hw(fmaxf(app ? (v.w - mn) * invden : v.w, 1e-12f));
        p[idx] = v;
    }
}

extern "C" void kernel_launch(void* const* d_in, const int* in_sizes, int n_in,
                              void* d_out, int out_size, void* d_ws, size_t ws_size,
                              hipStream_t stream) {
    (void)in_sizes; (void)n_in; (void)out_size;
    const float* raw = (const float*)d_in[0];
    const float* wb = (const float*)d_in[1];
    float* out = (float*)d_out;
    unsigned int* slots = (unsigned int*)d_ws;
    __half* hplanes = (__half*)((char*)d_ws + 4096);
    const size_t need = 4096 + (size_t)3 * IMG_H * IMG_W * sizeof(__half);
    const bool use_fp16 = ws_size >= need;

    init_slots<<<1, 512, 0, stream>>>(slots);
    dim3 grid(IMG_W / TS, IMG_H / TS);
    if (use_fp16) {
        demosaic_pass1<true><<<grid, 256, 0, stream>>>(raw, wb, out, hplanes, slots);
        finalize_pass2_h<<<dim3(2048), 256, 0, stream>>>(hplanes, out, slots);
    } else {
        demosaic_pass1<false><<<grid, 256, 0, stream>>>(raw, wb, out, hplanes, slots);
        finalize_pass2_f<<<dim3(2048), 256, 0, stream>>>(out, slots);
    }
}

// Round 17
// 158.608 us; speedup vs baseline: 1.0970x; 1.0970x over previous
//
#include <hip/hip_runtime.h>
#include <hip/hip_bf16.h>
#include <hip/hip_fp16.h>

// Menon 2007 demosaic (RGGB) + wb + clip + global minmax-normalize + gamma.
// Pass 1: fused tiled demosaic. GH/GV recomputed on the fly; D_H/D_V
//         parity-packed; stages A/B parity-specialized (literal p/q).
//         CFA rows STAGGERED (stride 48 + 4-float shift on alternate row
//         pairs). Best-measured configuration (124.8 us pass 1 / 158.9 total).
//         LDS 24064 B -> 6 blocks/CU. Output x*2^20 fp16 in d_ws.
// Pass 2: read fp16, normalize, gamma via v_log_f32/v_exp_f32 (HBM-bound).
//
// The M = (d_V >= d_H) classifier is a discrete decision on ~1e-5-scale values
// amplified ~4e4x by the normalize. The chain feeding M is BIT-EXACT vs numpy:
// contract off, true /65535.0f, reference accumulation order.
#pragma clang fp contract(off)

constexpr int IMG_H = 3072;
constexpr int IMG_W = 4096;
constexpr int TS = 32;
constexpr float GAMMA_E = (float)(1.0 / 2.2);
constexpr float SC = 1048576.0f;        // 2^20
constexpr float INV_SC = 1.0f / SC;

__device__ __forceinline__ int mir(int v, int n) {
    v = (v < 0) ? -v : v;
    return (v >= n) ? (2 * n - 2 - v) : v;
}

// ---- LDS layout (floats). CFA rows staggered; other strides odd-quad. ----
constexpr int CFA_ROWSP = 48;  // 12 quads + 4-float shift on alternate pairs
constexpr int D_STR   = 20;    // 5 quads (packed, non-green only)
constexpr int G_STR   = 36;    // 9 quads
constexpr int HV_STR  = 36;    // 9 quads
constexpr int OFF_CFA = 0;                 // 46 rows [-6,39], 44 cols used
constexpr int OFF_G   = 2204;              // 36 x 36 rows [-2,33]; M in low bit
constexpr int OFF_DH  = OFF_G + 36*36;     // 3500: 40 x 20 rows [-4,35]
constexpr int OFF_DV  = OFF_DH + 40*20;    // 4300
constexpr int OFF_HH  = OFF_DH;            // 34 x 36 (alias dead D)
constexpr int OFF_VV  = OFF_HH + 34*36;    // 4724
constexpr int SMEM_N  = OFF_VV + 34*36;    // 5948 floats = 23792 B

__device__ __forceinline__ int cfa_row(int rr) {
    return OFF_CFA + rr * CFA_ROWSP + (((rr) >> 1) & 1) * 4;
}

__global__ void init_slots(unsigned int* slots) {
    int t = threadIdx.x;
    if (t < 512) slots[t] = (t < 256) ? 0x7F800000u : 0u;
}

__device__ __forceinline__ float pack_gm(float g, unsigned mb) {
    return __uint_as_float((__float_as_uint(g) & ~1u) | mb);
}

template <bool FP16>
__global__ __launch_bounds__(256, 6) void demosaic_pass1(
    const float* __restrict__ raw, const float* __restrict__ wb,
    float* __restrict__ out, __half* __restrict__ hout,
    unsigned int* __restrict__ slots)
{
    __shared__ __align__(16) float sm[SMEM_N];
    __shared__ float redmn[4], redmx[4];
    const int tid = threadIdx.x;
    const int gr0 = blockIdx.y * TS;   // even
    const int gc0 = blockIdx.x * TS;   // even
    const bool fast = (blockIdx.x != 0) && (blockIdx.x != gridDim.x - 1) &&
                      (blockIdx.y != 0) && (blockIdx.y != gridDim.y - 1);

    if (fast) {
        // ---- Stage 0: global float4 -> LDS b128, exact /65535.0f ----
        const float* src = raw + (long long)(gr0 - 6) * IMG_W + (gc0 - 4);
        auto doLoad = [&](int ar, int qd) {
            float4 v = *(const float4*)(src + ar * IMG_W + (qd << 2));
            *(float4*)&sm[cfa_row(ar) + (qd << 2)] =
                make_float4(v.x / 65535.0f, v.y / 65535.0f, v.z / 65535.0f, v.w / 65535.0f);
        };
        for (int i = tid; i < 368; i += 256) doLoad(i >> 3, i & 7);
        for (int i = tid; i < 138; i += 256) doLoad(i / 3, 8 + (i % 3));
        __syncthreads();

        // ---- Stage A: packed D_H/D_V, parity-specialized (p literal) ----
        // Row ar <-> global r = gr0+ar-4 (CFA row ar+2). dl = 2k + p.
        auto doA = [&](int ar, int ku, int p) {
            const int cb = cfa_row(ar + 2) + 8 * ku;
            float w[16];
            {
                const float4 a = *(const float4*)&sm[cb];
                const float4 b = *(const float4*)&sm[cb + 4];
                const float4 c = *(const float4*)&sm[cb + 8];
                const float4 d = *(const float4*)&sm[cb + 12];
                w[0]=a.x; w[1]=a.y; w[2]=a.z; w[3]=a.w;
                w[4]=b.x; w[5]=b.y; w[6]=b.z; w[7]=b.w;
                w[8]=c.x; w[9]=c.y; w[10]=c.z; w[11]=c.w;
                w[12]=d.x; w[13]=d.y; w[14]=d.z; w[15]=d.w;
            }
            float cvj[7][4];  // rows ar..ar+6, cols cc = 8ku+2+2j+p
#pragma unroll
            for (int k = 0; k < 7; ++k) {
                if (k == 2) {
                    cvj[2][0]=w[2+p]; cvj[2][1]=w[4+p]; cvj[2][2]=w[6+p]; cvj[2][3]=w[8+p];
                    continue;
                }
                int rb = cfa_row(ar + k) + 8 * ku;
                float2 e  = *(const float2*)&sm[rb + 2];
                float4 f  = *(const float4*)&sm[rb + 4];
                float2 g2 = *(const float2*)&sm[rb + 8];
                if (p == 0) { cvj[k][0]=e.x; cvj[k][1]=f.x; cvj[k][2]=f.z; cvj[k][3]=g2.x; }
                else        { cvj[k][0]=e.y; cvj[k][1]=f.y; cvj[k][2]=f.w; cvj[k][3]=g2.y; }
            }
            auto ghe = [&](int wi) -> float {
                float x0 = w[wi];
                float t0 = 0.5f * w[wi-1] + 0.5f * w[wi+1];
                float t1 = (-0.25f * w[wi-2] + 0.5f * x0) + (-0.25f * w[wi+2]);
                return t0 + t1;
            };
            auto gve = [&](int k0, int j2) -> float {
                float x0 = cvj[k0][j2];
                float t0 = 0.5f * cvj[k0-1][j2] + 0.5f * cvj[k0+1][j2];
                float t1 = (-0.25f * cvj[k0-2][j2] + 0.5f * x0) + (-0.25f * cvj[k0+2][j2]);
                return t0 + t1;
            };
            float ch[5];
#pragma unroll
            for (int m = 0; m < 5; ++m) {
                int wi = 2 * m + 2 + p;
                ch[m] = w[wi] - ghe(wi);
            }
            float dhp[4], dvp[4];
#pragma unroll
            for (int j = 0; j < 4; ++j) {
                dhp[j] = fabsf(ch[j] - ch[j + 1]);
                float gv0 = gve(2, j), gv2 = gve(4, j);
                float cv0 = cvj[2][j] - gv0, cv2 = cvj[4][j] - gv2;
                dvp[j] = fabsf(cv0 - cv2);
            }
            *(float4*)&sm[OFF_DH + ar * D_STR + 4*ku] = make_float4(dhp[0],dhp[1],dhp[2],dhp[3]);
            *(float4*)&sm[OFF_DV + ar * D_STR + 4*ku] = make_float4(dvp[0],dvp[1],dvp[2],dvp[3]);
        };
        for (int i = tid; i < 100; i += 256) doA(2 * (i / 5), i % 5, 0);
        for (int i = tid; i < 100; i += 256) doA(2 * (i / 5) + 1, i % 5, 1);
        __syncthreads();

        // ---- Stage B: d_H/d_V -> M, G, parity-specialized (q literal) ----
        auto doB = [&](int ar, int ku, int q) {
            const int k4 = 4 * ku;
            float hw[6], vw[6], hu[4], hd[4], vu[4], vd[4];
            {
                int b0 = OFF_DH + (ar + 2) * D_STR + k4;
                float4 t = *(const float4*)&sm[b0]; hw[0]=t.x; hw[1]=t.y; hw[2]=t.z; hw[3]=t.w;
                float2 u = *(const float2*)&sm[b0 + 4]; hw[4]=u.x; hw[5]=u.y;
                float4 a = *(const float4*)&sm[OFF_DH + ar*D_STR + k4];     hu[0]=a.x; hu[1]=a.y; hu[2]=a.z; hu[3]=a.w;
                float4 b = *(const float4*)&sm[OFF_DH + (ar+4)*D_STR + k4]; hd[0]=b.x; hd[1]=b.y; hd[2]=b.z; hd[3]=b.w;
                int v0 = OFF_DV + (ar + 2) * D_STR + k4;
                float4 t2 = *(const float4*)&sm[v0]; vw[0]=t2.x; vw[1]=t2.y; vw[2]=t2.z; vw[3]=t2.w;
                float2 u2 = *(const float2*)&sm[v0 + 4]; vw[4]=u2.x; vw[5]=u2.y;
                float4 a2 = *(const float4*)&sm[OFF_DV + ar*D_STR + k4];     vu[0]=a2.x; vu[1]=a2.y; vu[2]=a2.z; vu[3]=a2.w;
                float4 b2 = *(const float4*)&sm[OFF_DV + (ar+4)*D_STR + k4]; vd[0]=b2.x; vd[1]=b2.y; vd[2]=b2.z; vd[3]=b2.w;
            }
            const int cb2 = cfa_row(ar + 4) + 8 * ku;   // CFA row of r (G row ar)
            float w2[12];
            {
                const float4 a = *(const float4*)&sm[cb2];
                const float4 b = *(const float4*)&sm[cb2 + 4];
                const float4 c = *(const float4*)&sm[cb2 + 8];
                w2[0]=a.x; w2[1]=a.y; w2[2]=a.z; w2[3]=a.w;
                w2[4]=b.x; w2[5]=b.y; w2[6]=b.z; w2[7]=b.w;
                w2[8]=c.x; w2[9]=c.y; w2[10]=c.z; w2[11]=c.w;
            }
            float cwj[5][4];  // CFA rows ar+2..ar+6, cols cc = 8ku+2+2j+q
#pragma unroll
            for (int k = 0; k < 5; ++k) {
                if (k == 2) {
                    cwj[2][0]=w2[2+q]; cwj[2][1]=w2[4+q]; cwj[2][2]=w2[6+q]; cwj[2][3]=w2[8+q];
                    continue;
                }
                int rb = cfa_row(ar + 2 + k) + 8 * ku;
                float2 e  = *(const float2*)&sm[rb + 2];
                float4 f  = *(const float4*)&sm[rb + 4];
                float2 g2 = *(const float2*)&sm[rb + 8];
                if (q == 0) { cwj[k][0]=e.x; cwj[k][1]=f.x; cwj[k][2]=f.z; cwj[k][3]=g2.x; }
                else        { cwj[k][0]=e.y; cwj[k][1]=f.y; cwj[k][2]=f.w; cwj[k][3]=g2.y; }
            }
            auto ghe2 = [&](int wi) -> float {
                float x0 = w2[wi];
                float t0 = 0.5f * w2[wi-1] + 0.5f * w2[wi+1];
                float t1 = (-0.25f * w2[wi-2] + 0.5f * x0) + (-0.25f * w2[wi+2]);
                return t0 + t1;
            };
            auto gve2 = [&](int j2) -> float {
                float x0 = cwj[2][j2];
                float t0 = 0.5f * cwj[1][j2] + 0.5f * cwj[3][j2];
                float t1 = (-0.25f * cwj[0][j2] + 0.5f * x0) + (-0.25f * cwj[4][j2]);
                return t0 + t1;
            };
            float gnb[4];
#pragma unroll
            for (int j = 0; j < 4; ++j) {
                float Dh0 = hw[j];
                float trowH = 3.0f*Dh0 + 3.0f*hw[j+1];
                float tcolH = (hu[j] + 3.0f*Dh0) + hd[j];
                float dH = (trowH + tcolH) - 3.0f*Dh0;
                float Dv0 = vw[j];
                float trowV = 3.0f*Dv0 + 3.0f*vw[j+1];
                float tcolV = (vu[j] + 3.0f*Dv0) + vd[j];
                float dV = (trowV + tcolV) - 3.0f*Dv0;
                unsigned mb = (dV >= dH) ? 1u : 0u;
                float gsel = mb ? ghe2(2*j + 2 + q) : gve2(j);
                gnb[j] = pack_gm(gsel, mb);
            }
            int gb = OFF_G + ar * G_STR + 8 * ku;
            if (q == 0) {
                *(float4*)&sm[gb] = make_float4(gnb[0], w2[3], gnb[1], w2[5]);
                if (ku < 4) *(float4*)&sm[gb+4] = make_float4(gnb[2], w2[7], gnb[3], w2[9]);
            } else {
                *(float4*)&sm[gb] = make_float4(w2[2], gnb[0], w2[4], gnb[1]);
                if (ku < 4) *(float4*)&sm[gb+4] = make_float4(w2[6], gnb[2], w2[8], gnb[3]);
            }
        };
        for (int i = tid; i < 90; i += 256) doB(2 * (i / 5), i % 5, 0);
        for (int i = tid; i < 90; i += 256) doB(2 * (i / 5) + 1, i % 5, 1);
        __syncthreads();

        // ---- Stage C: Hh/Vv (34 rows x 9 quads; alias dead D region) ----
        auto doC = [&](int ar, int hc4) {
            const float4 gmA = *(const float4*)&sm[OFF_G + (ar+1)*G_STR + hc4];
            const float4 gmB = *(const float4*)&sm[OFF_G + (ar+1)*G_STR + hc4 + 4];
            float gm[8] = {gmA.x,gmA.y,gmA.z,gmA.w, gmB.x,gmB.y,gmB.z,gmB.w};
            const float4 guA = *(const float4*)&sm[OFF_G + ar*G_STR + hc4];
            const float4 guB = *(const float4*)&sm[OFF_G + ar*G_STR + hc4 + 4];
            float gu[8] = {guA.x,guA.y,guA.z,guA.w, guB.x,guB.y,guB.z,guB.w};
            const float4 gdA = *(const float4*)&sm[OFF_G + (ar+2)*G_STR + hc4];
            const float4 gdB = *(const float4*)&sm[OFF_G + (ar+2)*G_STR + hc4 + 4];
            float gd[8] = {gdA.x,gdA.y,gdA.z,gdA.w, gdB.x,gdB.y,gdB.z,gdB.w};
            int c5 = cfa_row(ar + 5) + hc4;
            const float4 w5A = *(const float4*)&sm[c5];
            const float4 w5B = *(const float4*)&sm[c5 + 4];
            float w5[8] = {w5A.x,w5A.y,w5A.z,w5A.w, w5B.x,w5B.y,w5B.z,w5B.w};
            int c4i = cfa_row(ar + 4) + hc4;
            const float4 w4A = *(const float4*)&sm[c4i];
            const float4 w4B = *(const float4*)&sm[c4i + 4];
            float w4[8] = {w4A.x,w4A.y,w4A.z,w4A.w, w4B.x,w4B.y,w4B.z,w4B.w};
            int c6i = cfa_row(ar + 6) + hc4;
            const float4 w6A = *(const float4*)&sm[c6i];
            const float4 w6B = *(const float4*)&sm[c6i + 4];
            float w6[8] = {w6A.x,w6A.y,w6A.z,w6A.w, w6B.x,w6B.y,w6B.z,w6B.w};
            float oh[4], ov[4];
#pragma unroll
            for (int j = 0; j < 4; ++j) {
                float g0 = gm[j + 1];
                oh[j] = g0 + 0.5f * (w5[j + 2] + w5[j + 4] - gm[j] - gm[j + 2]);
                ov[j] = g0 + 0.5f * (w4[j + 3] + w6[j + 3] - gu[j + 1] - gd[j + 1]);
            }
            *(float4*)&sm[OFF_HH + ar * HV_STR + hc4] = make_float4(oh[0],oh[1],oh[2],oh[3]);
            *(float4*)&sm[OFF_VV + ar * HV_STR + hc4] = make_float4(ov[0],ov[1],ov[2],ov[3]);
        };
        for (int i = tid; i < 272; i += 256) doC(i >> 3, (i & 7) << 2);
        for (int i = tid; i < 34; i += 256) doC(i, 32);
    } else {
        // ---------- border path: scalar + mir (exact reflect semantics) ----------
        auto CFAb = [&](int r, int c) -> float { return sm[cfa_row(r - gr0 + 6) + (c - gc0 + 4)]; };
        auto Gb   = [&](int r, int c) -> float { return sm[OFF_G   + (r - gr0 + 2) * G_STR   + (c - gc0 + 2)]; };
        auto DHL  = [&](int r, int c) -> float {
            int dr = r - gr0 + 4;
            int kk = ((c - gc0 + 2) - (dr & 1)) >> 1;
            return sm[OFF_DH + dr * D_STR + kk];
        };
        auto DVL  = [&](int r, int c) -> float {
            int dr = r - gr0 + 4;
            int kk = ((c - gc0 + 2) - (dr & 1)) >> 1;
            return sm[OFF_DV + dr * D_STR + kk];
        };
        auto ghB = [&](int r, int c) -> float {
            float x0 = CFAb(r, c);
            float t0 = 0.5f * CFAb(r, c - 1) + 0.5f * CFAb(r, c + 1);
            float t1 = (-0.25f * CFAb(r, c - 2) + 0.5f * x0) + (-0.25f * CFAb(r, c + 2));
            return t0 + t1;
        };
        auto gvB = [&](int r, int c) -> float {
            float x0 = CFAb(r, c);
            float t0 = 0.5f * CFAb(r - 1, c) + 0.5f * CFAb(r + 1, c);
            float t1 = (-0.25f * CFAb(r - 2, c) + 0.5f * x0) + (-0.25f * CFAb(r + 2, c));
            return t0 + t1;
        };

        for (int i = tid; i < 46 * 44; i += 256) {
            int ar = i / 44, ac = i % 44;
            int r2 = mir(gr0 + ar - 6, IMG_H), c2 = mir(gc0 + ac - 4, IMG_W);
            sm[cfa_row(ar) + ac] = raw[r2 * IMG_W + c2] / 65535.0f;
        }
        __syncthreads();
        // Stage A border: packed D, k = 0..18 (k=19 unused)
        for (int i = tid; i < 40 * 19; i += 256) {
            int ar = i / 19, k = i % 19;
            int q = ar & 1, dl = 2 * k + q;
            int r2 = mir(gr0 + ar - 4, IMG_H), c2 = mir(gc0 + dl - 2, IMG_W);
            float ch0 = CFAb(r2, c2) - ghB(r2, c2);
            int c22 = mir(c2 + 2, IMG_W);
            float ch2 = CFAb(r2, c22) - ghB(r2, c22);
            sm[OFF_DH + ar * D_STR + k] = fabsf(ch0 - ch2);
            float cv0 = CFAb(r2, c2) - gvB(r2, c2);
            int r22 = mir(r2 + 2, IMG_H);
            float cv2 = CFAb(r22, c2) - gvB(r22, c2);
            sm[OFF_DV + ar * D_STR + k] = fabsf(cv0 - cv2);
        }
        __syncthreads();
        // Stage B border: full G plane (green copy; non-green M + selection)
        for (int i = tid; i < 36 * 36; i += 256) {
            int ar = i / 36, gc = i % 36;
            int r2 = mir(gr0 + ar - 2, IMG_H), c2 = mir(gc0 + gc - 2, IMG_W);
            float g;
            if ((r2 + c2) & 1) {
                g = CFAb(r2, c2);
            } else {
                float Dh0 = DHL(r2, c2);
                float trowH = 3.0f * Dh0 + 3.0f * DHL(r2, c2 + 2);
                float tcolH = (DHL(r2 - 2, c2) + 3.0f * Dh0) + DHL(r2 + 2, c2);
                float dH = (trowH + tcolH) - 3.0f * Dh0;
                float Dv0 = DVL(r2, c2);
                float trowV = 3.0f * Dv0 + 3.0f * DVL(r2, c2 + 2);
                float tcolV = (DVL(r2 - 2, c2) + 3.0f * Dv0) + DVL(r2 + 2, c2);
                float dV = (trowV + tcolV) - 3.0f * Dv0;
                unsigned mb = (dV >= dH) ? 1u : 0u;
                float gsel = mb ? ghB(r2, c2) : gvB(r2, c2);
                g = pack_gm(gsel, mb);
            }
            sm[OFF_G + ar * G_STR + gc] = g;
        }
        __syncthreads();
        // Stage C border
        for (int i = tid; i < 34 * 34; i += 256) {
            int ar = i / 34, ac = i % 34;
            int r2 = mir(gr0 + ar - 1, IMG_H), c2 = mir(gc0 + ac - 1, IMG_W);
            float g0 = Gb(r2, c2);
            float hh = g0 + 0.5f * (CFAb(r2, c2 - 1) + CFAb(r2, c2 + 1) - Gb(r2, c2 - 1) - Gb(r2, c2 + 1));
            float vv = g0 + 0.5f * (CFAb(r2 - 1, c2) + CFAb(r2 + 1, c2) - Gb(r2 - 1, c2) - Gb(r2 + 1, c2));
            sm[OFF_HH + ar * HV_STR + ac] = hh;
            sm[OFF_VV + ar * HV_STR + ac] = vv;
        }
        __syncthreads();   // extra barrier to match fast path count
    }
    __syncthreads();

    // ---------- final per-pixel: 1 row x 4 cols per thread ----------
    const float wr = wb[0], wg = wb[1], wbv = wb[2];
    const int pr = tid >> 3;
    const int pc0 = (tid & 7) << 2;
    const bool rowOdd = (pr & 1) != 0;      // gr0 even
    int hbase = OFF_HH + (pr + 1) * HV_STR + pc0;
    const float4 h1a = *(const float4*)&sm[hbase];
    const float4 h1b = *(const float4*)&sm[hbase + 4];
    float hwc[8] = {h1a.x, h1a.y, h1a.z, h1a.w, h1b.x, h1b.y, h1b.z, h1b.w};
    int vbase = OFF_VV + (pr + 1) * HV_STR + pc0;
    const float4 v1a = *(const float4*)&sm[vbase];
    const float4 v1b = *(const float4*)&sm[vbase + 4];
    float vwc[8] = {v1a.x, v1a.y, v1a.z, v1a.w, v1b.x, v1b.y, v1b.z, v1b.w};
    const float4 huA = *(const float4*)&sm[OFF_HH + pr * HV_STR + pc0];
    const float4 huB = *(const float4*)&sm[OFF_HH + pr * HV_STR + pc0 + 4];
    float hu[6] = {huA.x, huA.y, huA.z, huA.w, huB.x, huB.y};
    const float4 hdA = *(const float4*)&sm[OFF_HH + (pr + 2) * HV_STR + pc0];
    const float4 hdB = *(const float4*)&sm[OFF_HH + (pr + 2) * HV_STR + pc0 + 4];
    float hd[6] = {hdA.x, hdA.y, hdA.z, hdA.w, hdB.x, hdB.y};
    const float4 vuA = *(const float4*)&sm[OFF_VV + pr * HV_STR + pc0];
    const float4 vuB = *(const float4*)&sm[OFF_VV + pr * HV_STR + pc0 + 4];
    float vu[6] = {vuA.x, vuA.y, vuA.z, vuA.w, vuB.x, vuB.y};
    const float4 vdA = *(const float4*)&sm[OFF_VV + (pr + 2) * HV_STR + pc0];
    const float4 vdB = *(const float4*)&sm[OFF_VV + (pr + 2) * HV_STR + pc0 + 4];
    float vd[6] = {vdA.x, vdA.y, vdA.z, vdA.w, vdB.x, vdB.y};
    const float4 cfq = *(const float4*)&sm[cfa_row(pr + 6) + pc0 + 4];
    float cf[4] = {cfq.x, cfq.y, cfq.z, cfq.w};
    const float4 gA = *(const float4*)&sm[OFF_G + (pr + 2) * G_STR + pc0];
    const float4 gB = *(const float4*)&sm[OFF_G + (pr + 2) * G_STR + pc0 + 4];
    float ggr[4] = {gA.z, gA.w, gB.x, gB.y};

    float mn = 1e30f, mx = -1e30f;
    float rr[4], go[4], bo[4];
    __half hR[4], hG[4], hB[4];
#pragma unroll
    for (int j = 0; j < 4; ++j) {
        const float cfa = cf[j];
        const float g = ggr[j];
        const unsigned mb = __float_as_uint(g) & 1u;
        float sH = (hwc[j] - vwc[j]) + (hwc[j + 2] - vwc[j + 2]);
        float sV = (hu[j + 1] - vu[j + 1]) + (hd[j + 1] - vd[j + 1]);
        float X = mb ? (cfa - 0.5f * sH) : (cfa + 0.5f * sV);
        float R, B;
        if ((j & 1) == 0) {             // col even
            R = rowOdd ? vwc[j + 1] : cfa;
            B = rowOdd ? hwc[j + 1] : X;
        } else {                        // col odd
            R = rowOdd ? X : hwc[j + 1];
            B = rowOdd ? cfa : vwc[j + 1];
        }
        R = fminf(fmaxf(R * wr, 0.f), 1.f);
        float Gx = fminf(fmaxf(g * wg, 0.f), 1.f);
        B = fminf(fmaxf(B * wbv, 0.f), 1.f);
        if constexpr (FP16) {
            hR[j] = __float2half(R * SC);  R  = __half2float(hR[j]);
            hG[j] = __float2half(Gx * SC); Gx = __half2float(hG[j]);
            hB[j] = __float2half(B * SC);  B  = __half2float(hB[j]);
        }
        mn = fminf(mn, fminf(R, fminf(Gx, B)));
        mx = fmaxf(mx, fmaxf(R, fmaxf(Gx, B)));
        rr[j] = R; go[j] = Gx; bo[j] = B;
    }
    const long long HW = (long long)IMG_H * IMG_W;
    const long long base = (long long)(gr0 + pr) * IMG_W + (gc0 + pc0);
    if constexpr (FP16) {
        auto pack = [](__half a, __half b) {
            __half2 p = __halves2half2(a, b);
            return *reinterpret_cast<unsigned int*>(&p);
        };
        *(uint2*)(hout + base)          = make_uint2(pack(hR[0], hR[1]), pack(hR[2], hR[3]));
        *(uint2*)(hout + HW + base)     = make_uint2(pack(hG[0], hG[1]), pack(hG[2], hG[3]));
        *(uint2*)(hout + 2 * HW + base) = make_uint2(pack(hB[0], hB[1]), pack(hB[2], hB[3]));
    } else {
        *(float4*)(out + base)          = make_float4(rr[0], rr[1], rr[2], rr[3]);
        *(float4*)(out + HW + base)     = make_float4(go[0], go[1], go[2], go[3]);
        *(float4*)(out + 2 * HW + base) = make_float4(bo[0], bo[1], bo[2], bo[3]);
    }

#pragma unroll
    for (int off2 = 32; off2 > 0; off2 >>= 1) {
        mn = fminf(mn, __shfl_xor(mn, off2));
        mx = fmaxf(mx, __shfl_xor(mx, off2));
    }
    if ((tid & 63) == 0) { redmn[tid >> 6] = mn; redmx[tid >> 6] = mx; }
    __syncthreads();
    if (tid == 0) {
        mn = fminf(fminf(redmn[0], redmn[1]), fminf(redmn[2], redmn[3]));
        mx = fmaxf(fmaxf(redmx[0], redmx[1]), fmaxf(redmx[2], redmx[3]));
        if constexpr (FP16) { mn *= INV_SC; mx *= INV_SC; }
        int slot = (int)((blockIdx.y * gridDim.x + blockIdx.x) & 255);
        atomicMin(&slots[slot], __float_as_uint(mn));
        atomicMax(&slots[256 + slot], __float_as_uint(mx));
    }
}

__device__ __forceinline__ void reduce_slots(const unsigned int* slots, int tid,
                                             float* smn, float* smx, float& mn, float& mx) {
    mn = __uint_as_float(slots[tid]);
    mx = __uint_as_float(slots[256 + tid]);
#pragma unroll
    for (int off2 = 32; off2 > 0; off2 >>= 1) {
        mn = fminf(mn, __shfl_xor(mn, off2));
        mx = fmaxf(mx, __shfl_xor(mx, off2));
    }
    if ((tid & 63) == 0) { smn[tid >> 6] = mn; smx[tid >> 6] = mx; }
    __syncthreads();
    mn = fminf(fminf(smn[0], smn[1]), fminf(smn[2], smn[3]));
    mx = fmaxf(fmaxf(smx[0], smx[1]), fmaxf(smx[2], smx[3]));
}

__device__ __forceinline__ float gamma_hw(float a) {
    return __builtin_amdgcn_exp2f(GAMMA_E * __builtin_amdgcn_logf(a));
}

__global__ __launch_bounds__(256) void finalize_pass2_h(
    const __half* __restrict__ hin, float* __restrict__ out,
    const unsigned int* __restrict__ slots)
{
    __shared__ float smn[4], smx[4];
    const int tid = threadIdx.x;
    float mn, mx;
    reduce_slots(slots, tid, smn, smx, mn, mx);
    const float rng = mx - mn;
    const bool app = rng > 1e-6f;
    const float invden = 1.0f / fmaxf(rng, 1e-12f);

    const long long n8 = (long long)3 * IMG_H * IMG_W / 8;
    const uint4* pin = (const uint4*)hin;
    float4* po = (float4*)out;
    for (long long idx = (long long)blockIdx.x * blockDim.x + tid; idx < n8;
         idx += (long long)gridDim.x * blockDim.x) {
        uint4 u = pin[idx];
        float f[8];
        float2 t;
        t = __half22float2(*(__half2*)&u.x); f[0] = t.x; f[1] = t.y;
        t = __half22float2(*(__half2*)&u.y); f[2] = t.x; f[3] = t.y;
        t = __half22float2(*(__half2*)&u.z); f[4] = t.x; f[5] = t.y;
        t = __half22float2(*(__half2*)&u.w); f[6] = t.x; f[7] = t.y;
#pragma unroll
        for (int k = 0; k < 8; ++k) {
            float a = f[k] * INV_SC;
            a = app ? (a - mn) * invden : a;
            f[k] = gamma_hw(fmaxf(a, 1e-12f));
        }
        po[2 * idx]     = make_float4(f[0], f[1], f[2], f[3]);
        po[2 * idx + 1] = make_float4(f[4], f[5], f[6], f[7]);
    }
}

__global__ __launch_bounds__(256) void finalize_pass2_f(
    float* __restrict__ out, const unsigned int* __restrict__ slots)
{
    __shared__ float smn[4], smx[4];
    const int tid = threadIdx.x;
    float mn, mx;
    reduce_slots(slots, tid, smn, smx, mn, mx);
    const float rng = mx - mn;
    const bool app = rng > 1e-6f;
    const float invden = 1.0f / fmaxf(rng, 1e-12f);

    const long long n4 = (long long)3 * IMG_H * IMG_W / 4;
    float4* p = (float4*)out;
    for (long long idx = (long long)blockIdx.x * blockDim.x + tid; idx < n4;
         idx += (long long)gridDim.x * blockDim.x) {
        float4 v = p[idx];
        v.x = gamma_hw(fmaxf(app ? (v.x - mn) * invden : v.x, 1e-12f));
        v.y = gamma_hw(fmaxf(app ? (v.y - mn) * invden : v.y, 1e-12f));
        v.z = gamma_hw(fmaxf(app ? (v.z - mn) * invden : v.z, 1e-12f));
        v.w = gamma_hw(fmaxf(app ? (v.w - mn) * invden : v.w, 1e-12f));
        p[idx] = v;
    }
}

extern "C" void kernel_launch(void* const* d_in, const int* in_sizes, int n_in,
                              void* d_out, int out_size, void* d_ws, size_t ws_size,
                              hipStream_t stream) {
    (void)in_sizes; (void)n_in; (void)out_size;
    const float* raw = (const float*)d_in[0];
    const float* wb = (const float*)d_in[1];
    float* out = (float*)d_out;
    unsigned int* slots = (unsigned int*)d_ws;
    __half* hplanes = (__half*)((char*)d_ws + 4096);
    const size_t need = 4096 + (size_t)3 * IMG_H * IMG_W * sizeof(__half);
    const bool use_fp16 = ws_size >= need;

    init_slots<<<1, 512, 0, stream>>>(slots);
    dim3 grid(IMG_W / TS, IMG_H / TS);
    if (use_fp16) {
        demosaic_pass1<true><<<grid, 256, 0, stream>>>(raw, wb, out, hplanes, slots);
        finalize_pass2_h<<<dim3(2048), 256, 0, stream>>>(hplanes, out, slots);
    } else {
        demosaic_pass1<false><<<grid, 256, 0, stream>>>(raw, wb, out, hplanes, slots);
        finalize_pass2_f<<<dim3(2048), 256, 0, stream>>>(out, slots);
    }
}